// Round 2
// baseline (788.727 us; speedup 1.0000x reference)
//
#include <hip/hip_runtime.h>

#define NXCD 8

__device__ __forceinline__ int xcc_id() {
    int x;
    asm volatile("s_getreg_b32 %0, hwreg(HW_REG_XCC_ID)" : "=s"(x));
    return x & 0xf;
}

// Per-XCD-copy scatter-add with workgroup-scope atomics (execute in local L2,
// no write-through). acc has NXCD copies of n_vert floats; each block adds
// only into its own XCD's copy.
__global__ void scatter_add_xcd_kernel(const int* __restrict__ dst,
                                       const float* __restrict__ ea,
                                       float* __restrict__ acc,
                                       int n_edges4, int n_vert) {
    float* my = acc + (size_t)xcc_id() * n_vert;
    int i = blockIdx.x * blockDim.x + threadIdx.x;
    const int stride = gridDim.x * blockDim.x;
    for (; i < n_edges4; i += stride) {
        int4   d = reinterpret_cast<const int4*>(dst)[i];
        float4 v = reinterpret_cast<const float4*>(ea)[i];
        __hip_atomic_fetch_add(&my[d.x], v.x, __ATOMIC_RELAXED, __HIP_MEMORY_SCOPE_WORKGROUP);
        __hip_atomic_fetch_add(&my[d.y], v.y, __ATOMIC_RELAXED, __HIP_MEMORY_SCOPE_WORKGROUP);
        __hip_atomic_fetch_add(&my[d.z], v.z, __ATOMIC_RELAXED, __HIP_MEMORY_SCOPE_WORKGROUP);
        __hip_atomic_fetch_add(&my[d.w], v.w, __ATOMIC_RELAXED, __HIP_MEMORY_SCOPE_WORKGROUP);
    }
}

// Fallback: single-copy device-scope atomics (round-1 behavior).
__global__ void scatter_add_dev_kernel(const int* __restrict__ dst,
                                       const float* __restrict__ ea,
                                       float* __restrict__ acc,
                                       int n_edges4) {
    int i = blockIdx.x * blockDim.x + threadIdx.x;
    const int stride = gridDim.x * blockDim.x;
    for (; i < n_edges4; i += stride) {
        int4   d = reinterpret_cast<const int4*>(dst)[i];
        float4 v = reinterpret_cast<const float4*>(ea)[i];
        atomicAdd(&acc[d.x], v.x);
        atomicAdd(&acc[d.y], v.y);
        atomicAdd(&acc[d.z], v.z);
        atomicAdd(&acc[d.w], v.w);
    }
}

// cbar_i = sum over copies; out[i] = {A, b, x + w*(b - cbar)/A}
__global__ void reduce_update_kernel(const float* __restrict__ va,
                                     const float* __restrict__ acc,
                                     const float* __restrict__ g,
                                     float* __restrict__ out,
                                     int n, int ncopies) {
    int i = blockIdx.x * blockDim.x + threadIdx.x;
    if (i >= n) return;
    float c = 0.f;
    for (int k = 0; k < ncopies; ++k)
        c += acc[(size_t)k * n + i];
    float A = va[3 * i + 0];
    float b = va[3 * i + 1];
    float x = va[3 * i + 2];
    float w = g[0];
    out[3 * i + 0] = A;
    out[3 * i + 1] = b;
    out[3 * i + 2] = x + w * (b - c) / A;
}

extern "C" void kernel_launch(void* const* d_in, const int* in_sizes, int n_in,
                              void* d_out, int out_size, void* d_ws, size_t ws_size,
                              hipStream_t stream) {
    const float* vertex_attr = (const float*)d_in[0];   // (N,3)
    const int*   edgeij      = (const int*)d_in[1];     // (2, E); row 0 = dst
    const float* edge_attr   = (const float*)d_in[2];   // (E,1)
    const float* g           = (const float*)d_in[3];   // (1,)

    const int n_vert = in_sizes[0] / 3;
    const int n_edge = in_sizes[2];
    const int n_edges4 = n_edge / 4;

    float* acc = (float*)d_ws;
    const size_t need = (size_t)NXCD * n_vert * sizeof(float);
    const int ncopies = (ws_size >= need) ? NXCD : 1;

    // Zero accumulator copies every call (ws is not re-poisoned between replays).
    hipMemsetAsync(acc, 0, (size_t)ncopies * n_vert * sizeof(float), stream);

    const int sb = 256;
    const int sg = 4096;   // grid-stride; plenty of waves for atomic latency hiding
    if (ncopies == NXCD) {
        scatter_add_xcd_kernel<<<sg, sb, 0, stream>>>(edgeij, edge_attr, acc,
                                                      n_edges4, n_vert);
    } else {
        scatter_add_dev_kernel<<<sg, sb, 0, stream>>>(edgeij, edge_attr, acc,
                                                      n_edges4);
    }

    const int ub = 256;
    const int ug = (n_vert + ub - 1) / ub;
    reduce_update_kernel<<<ug, ub, 0, stream>>>(vertex_attr, acc, g,
                                                (float*)d_out, n_vert, ncopies);
}

// Round 3
// 419.112 us; speedup vs baseline: 1.8819x; 1.8819x over previous
//
#include <hip/hip_runtime.h>

#define TPB    256
#define VSHIFT 12
#define VBUCK  (1 << VSHIFT)        // 4096 vertices per bucket
#define NBMAX  256                  // max buckets (1e6/4096 = 245)
#define MAXCH  16                   // max chunks
#define HK     32                   // edges/thread, histogram  -> 8192/block
#define PK     64                   // edges/thread, partition  -> 16384/block
#define HBLK   (TPB * HK)
#define PBLK   (TPB * PK)

__device__ __forceinline__ unsigned long long pack_pair(int d, float v) {
    return (unsigned long long)(unsigned)d |
           ((unsigned long long)__float_as_uint(v) << 32);
}

// Per-chunk bucket histogram of dst.
__global__ void hist_kernel(const int* __restrict__ dst, long long n_edge,
                            int chunk_edges, int blocks_per_chunk, int nb,
                            int* __restrict__ hist /* [MAXCH][NBMAX] */) {
    __shared__ int h[NBMAX];
    for (int t = threadIdx.x; t < NBMAX; t += TPB) h[t] = 0;
    __syncthreads();
    const int chunk = blockIdx.x / blocks_per_chunk;
    const int bio   = blockIdx.x % blocks_per_chunk;
    const long long cstart = (long long)chunk * chunk_edges;
    const long long cend0  = cstart + chunk_edges;
    const long long cend   = cend0 < n_edge ? cend0 : n_edge;
    const long long base   = cstart + (long long)bio * HBLK;
    #pragma unroll 4
    for (int j = 0; j < HK / 4; ++j) {
        long long e = base + ((long long)j * TPB + threadIdx.x) * 4;
        if (e + 4 <= cend) {
            int4 d = *reinterpret_cast<const int4*>(dst + e);
            atomicAdd(&h[d.x >> VSHIFT], 1);
            atomicAdd(&h[d.y >> VSHIFT], 1);
            atomicAdd(&h[d.z >> VSHIFT], 1);
            atomicAdd(&h[d.w >> VSHIFT], 1);
        } else {
            for (int q = 0; q < 4; ++q) {
                long long ee = e + q;
                if (ee < cend) atomicAdd(&h[dst[ee] >> VSHIFT], 1);
            }
        }
    }
    __syncthreads();
    for (int t = threadIdx.x; t < nb; t += TPB) {
        int c = h[t];
        if (c) atomicAdd(&hist[chunk * NBMAX + t], c);
    }
}

// Exclusive scan per chunk: hist -> bucket base offsets; cursor = copy.
__global__ void scan_kernel(int* __restrict__ hist, int* __restrict__ cursor,
                            int nchunks, int nb) {
    int c = blockIdx.x * blockDim.x + threadIdx.x;
    if (c < nchunks) {
        int run = 0;
        for (int b = 0; b < nb; ++b) {
            int v = hist[c * NBMAX + b];
            hist[c * NBMAX + b]   = run;
            cursor[c * NBMAX + b] = run;
            run += v;
        }
    }
}

// Partition one chunk's edges into per-bucket (dst,val) pair regions.
__global__ void partition_kernel(const int* __restrict__ dst,
                                 const float* __restrict__ ea,
                                 long long cstart, long long cend, int nb,
                                 int* __restrict__ cursor,
                                 unsigned long long* __restrict__ pairs) {
    __shared__ int h[NBMAX];
    __shared__ int cur[NBMAX];
    for (int t = threadIdx.x; t < NBMAX; t += TPB) h[t] = 0;
    __syncthreads();
    const long long base = cstart + (long long)blockIdx.x * PBLK;
    // pass 1: block-local histogram
    #pragma unroll 4
    for (int j = 0; j < PK / 4; ++j) {
        long long e = base + ((long long)j * TPB + threadIdx.x) * 4;
        if (e + 4 <= cend) {
            int4 d = *reinterpret_cast<const int4*>(dst + e);
            atomicAdd(&h[d.x >> VSHIFT], 1);
            atomicAdd(&h[d.y >> VSHIFT], 1);
            atomicAdd(&h[d.z >> VSHIFT], 1);
            atomicAdd(&h[d.w >> VSHIFT], 1);
        } else {
            for (int q = 0; q < 4; ++q) {
                long long ee = e + q;
                if (ee < cend) atomicAdd(&h[dst[ee] >> VSHIFT], 1);
            }
        }
    }
    __syncthreads();
    // reserve global space: one atomic per (block,bucket)
    for (int t = threadIdx.x; t < nb; t += TPB) {
        int c = h[t];
        cur[t] = c ? atomicAdd(&cursor[t], c) : 0;
    }
    __syncthreads();
    // pass 2: scatter pairs
    #pragma unroll 4
    for (int j = 0; j < PK / 4; ++j) {
        long long e = base + ((long long)j * TPB + threadIdx.x) * 4;
        if (e + 4 <= cend) {
            int4   d = *reinterpret_cast<const int4*>(dst + e);
            float4 v = *reinterpret_cast<const float4*>(ea + e);
            int s0 = atomicAdd(&cur[d.x >> VSHIFT], 1); pairs[s0] = pack_pair(d.x, v.x);
            int s1 = atomicAdd(&cur[d.y >> VSHIFT], 1); pairs[s1] = pack_pair(d.y, v.y);
            int s2 = atomicAdd(&cur[d.z >> VSHIFT], 1); pairs[s2] = pack_pair(d.z, v.z);
            int s3 = atomicAdd(&cur[d.w >> VSHIFT], 1); pairs[s3] = pack_pair(d.w, v.w);
        } else {
            for (int q = 0; q < 4; ++q) {
                long long ee = e + q;
                if (ee < cend) {
                    int dv = dst[ee]; float vv = ea[ee];
                    int s = atomicAdd(&cur[dv >> VSHIFT], 1);
                    pairs[s] = pack_pair(dv, vv);
                }
            }
        }
    }
}

// One block per bucket: accumulate pairs into LDS, then add into cbar.
__global__ void accum_kernel(const unsigned long long* __restrict__ pairs,
                             const int* __restrict__ bases, int nb,
                             int chunk_count,
                             float* __restrict__ cbar, int n_vert) {
    __shared__ float acc[VBUCK];
    const int b = blockIdx.x;
    for (int t = threadIdx.x; t < VBUCK; t += blockDim.x) acc[t] = 0.f;
    __syncthreads();
    const int s = bases[b];
    const int e = (b + 1 < nb) ? bases[b + 1] : chunk_count;
    for (int i = s + threadIdx.x; i < e; i += blockDim.x) {
        unsigned long long p = pairs[i];
        int   dv = (int)(p & 0xffffffffull);
        float vv = __uint_as_float((unsigned)(p >> 32));
        atomicAdd(&acc[dv & (VBUCK - 1)], vv);
    }
    __syncthreads();
    const int vbase = b << VSHIFT;
    for (int t = threadIdx.x; t < VBUCK; t += blockDim.x) {
        int vi = vbase + t;
        if (vi < n_vert) cbar[vi] += acc[t];
    }
}

// Fallback: device-scope atomic scatter (round-1 path).
__global__ void scatter_add_dev_kernel(const int* __restrict__ dst,
                                       const float* __restrict__ ea,
                                       float* __restrict__ acc, int n_edges4) {
    int i = blockIdx.x * blockDim.x + threadIdx.x;
    const int stride = gridDim.x * blockDim.x;
    for (; i < n_edges4; i += stride) {
        int4   d = reinterpret_cast<const int4*>(dst)[i];
        float4 v = reinterpret_cast<const float4*>(ea)[i];
        atomicAdd(&acc[d.x], v.x);
        atomicAdd(&acc[d.y], v.y);
        atomicAdd(&acc[d.z], v.z);
        atomicAdd(&acc[d.w], v.w);
    }
}

__global__ void update_kernel(const float* __restrict__ va,
                              const float* __restrict__ cbar,
                              const float* __restrict__ g,
                              float* __restrict__ out, int n) {
    int i = blockIdx.x * blockDim.x + threadIdx.x;
    if (i >= n) return;
    float A = va[3 * i], b = va[3 * i + 1], x = va[3 * i + 2];
    out[3 * i]     = A;
    out[3 * i + 1] = b;
    out[3 * i + 2] = x + g[0] * (b - cbar[i]) / A;
}

extern "C" void kernel_launch(void* const* d_in, const int* in_sizes, int n_in,
                              void* d_out, int out_size, void* d_ws, size_t ws_size,
                              hipStream_t stream) {
    const float* vertex_attr = (const float*)d_in[0];
    const int*   edgeij      = (const int*)d_in[1];   // row 0 = dst
    const float* edge_attr   = (const float*)d_in[2];
    const float* g           = (const float*)d_in[3];

    const int       n_vert = in_sizes[0] / 3;
    const long long n_edge = in_sizes[2];
    const int       nb     = (n_vert + VBUCK - 1) >> VSHIFT;

    // ws layout: [cbar][hist bases][cursors][pairs]
    size_t cbar_sz   = (size_t)n_vert * sizeof(float);
    size_t hist_off  = (cbar_sz + 255) & ~(size_t)255;
    size_t hist_sz   = (size_t)MAXCH * NBMAX * sizeof(int);
    size_t cur_off   = hist_off + hist_sz;
    size_t pairs_off = (cur_off + hist_sz + 255) & ~(size_t)255;

    float* cbar  = (float*)d_ws;
    int* hist    = (int*)((char*)d_ws + hist_off);
    int* cursor  = (int*)((char*)d_ws + cur_off);
    unsigned long long* pairs = (unsigned long long*)((char*)d_ws + pairs_off);

    long long cap = (ws_size > pairs_off) ? (long long)((ws_size - pairs_off) / 8) : 0;
    cap = (cap / PBLK) * PBLK;

    int nchunks = 0;
    long long chunk_edges = 0;
    if (cap >= PBLK) {
        nchunks = (int)((n_edge + cap - 1) / cap);
        if (nchunks <= MAXCH) {
            chunk_edges = (n_edge + nchunks - 1) / nchunks;
            chunk_edges = ((chunk_edges + PBLK - 1) / PBLK) * PBLK;
            if (chunk_edges > cap) chunk_edges = cap;
            nchunks = (int)((n_edge + chunk_edges - 1) / chunk_edges);
        } else {
            nchunks = 0;
        }
    }

    hipMemsetAsync(cbar, 0, cbar_sz, stream);

    if (nchunks == 0 || nchunks > MAXCH) {
        // not enough scratch: atomic fallback
        scatter_add_dev_kernel<<<4096, TPB, 0, stream>>>(edgeij, edge_attr, cbar,
                                                         (int)(n_edge / 4));
    } else {
        hipMemsetAsync(hist, 0, 2 * hist_sz, stream);
        int bpc = (int)(chunk_edges / HBLK);
        hist_kernel<<<nchunks * bpc, TPB, 0, stream>>>(edgeij, n_edge,
                                                       (int)chunk_edges, bpc, nb, hist);
        scan_kernel<<<1, 64, 0, stream>>>(hist, cursor, nchunks, nb);
        for (int c = 0; c < nchunks; ++c) {
            long long cstart = (long long)c * chunk_edges;
            long long cend   = cstart + chunk_edges;
            if (cend > n_edge) cend = n_edge;
            int pblocks = (int)((cend - cstart + PBLK - 1) / PBLK);
            partition_kernel<<<pblocks, TPB, 0, stream>>>(edgeij, edge_attr,
                                                          cstart, cend, nb,
                                                          cursor + c * NBMAX, pairs);
            accum_kernel<<<nb, 512, 0, stream>>>(pairs, hist + c * NBMAX, nb,
                                                 (int)(cend - cstart), cbar, n_vert);
        }
    }

    update_kernel<<<(n_vert + TPB - 1) / TPB, TPB, 0, stream>>>(
        vertex_attr, cbar, g, (float*)d_out, n_vert);
}

// Round 4
// 273.598 us; speedup vs baseline: 2.8828x; 1.5319x over previous
//
#include <hip/hip_runtime.h>

#define TPB    256
#define VSHIFT 12
#define VBUCK  (1 << VSHIFT)        // 4096 vertices per bucket
#define NBMAX  256                  // max buckets (1e6/4096 = 245); == TPB
#define MAXCH  16                   // max chunks
#define HK     32                   // edges/thread, histogram  -> 8192/block
#define EPT    16                   // edges/thread/round, partition
#define ROUND  (TPB * EPT)          // 4096 edges/round
#define RPB    4                    // rounds per block
#define PBLK   (ROUND * RPB)        // 16384 edges/block
#define HBLK   (TPB * HK)

__device__ __forceinline__ unsigned long long pack_pair(int d, float v) {
    return (unsigned long long)(unsigned)d |
           ((unsigned long long)__float_as_uint(v) << 32);
}

// Per-chunk bucket histogram of dst.
__global__ void hist_kernel(const int* __restrict__ dst, long long n_edge,
                            int chunk_edges, int blocks_per_chunk, int nb,
                            int* __restrict__ hist /* [MAXCH][NBMAX] */) {
    __shared__ int h[NBMAX];
    for (int t = threadIdx.x; t < NBMAX; t += TPB) h[t] = 0;
    __syncthreads();
    const int chunk = blockIdx.x / blocks_per_chunk;
    const int bio   = blockIdx.x % blocks_per_chunk;
    const long long cstart = (long long)chunk * chunk_edges;
    const long long cend0  = cstart + chunk_edges;
    const long long cend   = cend0 < n_edge ? cend0 : n_edge;
    const long long base   = cstart + (long long)bio * HBLK;
    #pragma unroll 4
    for (int j = 0; j < HK / 4; ++j) {
        long long e = base + ((long long)j * TPB + threadIdx.x) * 4;
        if (e + 4 <= cend) {
            int4 d = *reinterpret_cast<const int4*>(dst + e);
            atomicAdd(&h[d.x >> VSHIFT], 1);
            atomicAdd(&h[d.y >> VSHIFT], 1);
            atomicAdd(&h[d.z >> VSHIFT], 1);
            atomicAdd(&h[d.w >> VSHIFT], 1);
        } else {
            for (int q = 0; q < 4; ++q) {
                long long ee = e + q;
                if (ee < cend) atomicAdd(&h[dst[ee] >> VSHIFT], 1);
            }
        }
    }
    __syncthreads();
    for (int t = threadIdx.x; t < nb; t += TPB) {
        int c = h[t];
        if (c) atomicAdd(&hist[chunk * NBMAX + t], c);
    }
}

// Exclusive scan per chunk: hist -> bucket base offsets; cursor = copy.
__global__ void scan_kernel(int* __restrict__ hist, int* __restrict__ cursor,
                            int nchunks, int nb) {
    int c = blockIdx.x * blockDim.x + threadIdx.x;
    if (c < nchunks) {
        int run = 0;
        for (int b = 0; b < nb; ++b) {
            int v = hist[c * NBMAX + b];
            hist[c * NBMAX + b]   = run;
            cursor[c * NBMAX + b] = run;
            run += v;
        }
    }
}

// Partition one chunk's edges into per-bucket (dst,val) pair regions,
// with LDS-staged bucket-sorted flush for coalesced global writes.
__global__ __launch_bounds__(TPB, 4)
void partition_kernel(const int* __restrict__ dst,
                      const float* __restrict__ ea,
                      long long cstart, long long cend, int nb,
                      int* __restrict__ cursor,
                      unsigned long long* __restrict__ pairs) {
    __shared__ unsigned long long stage[ROUND];   // 32 KB, bucket-sorted pairs
    __shared__ int hall[NBMAX];   // block-total histogram
    __shared__ int h[NBMAX];      // round histogram
    __shared__ int pfx[NBMAX];    // round exclusive prefix
    __shared__ int pos[NBMAX];    // round scatter cursors
    __shared__ int adj[NBMAX];    // goff+done-pfx per bucket
    __shared__ int goff[NBMAX];   // reserved global base per bucket
    __shared__ int done[NBMAX];   // pairs already flushed per bucket
    __shared__ int wsum[TPB / 64];
    __shared__ int round_total;

    const int t = threadIdx.x;
    const long long bbase = cstart + (long long)blockIdx.x * PBLK;

    hall[t] = 0;
    __syncthreads();

    // Pass A: block-total histogram over all PBLK edges.
    #pragma unroll 4
    for (int j = 0; j < PBLK / TPB / 4; ++j) {
        long long e = bbase + ((long long)j * TPB + t) * 4;
        if (e + 4 <= cend) {
            int4 d = *reinterpret_cast<const int4*>(dst + e);
            atomicAdd(&hall[d.x >> VSHIFT], 1);
            atomicAdd(&hall[d.y >> VSHIFT], 1);
            atomicAdd(&hall[d.z >> VSHIFT], 1);
            atomicAdd(&hall[d.w >> VSHIFT], 1);
        } else {
            for (int q = 0; q < 4; ++q) {
                long long ee = e + q;
                if (ee < cend) atomicAdd(&hall[dst[ee] >> VSHIFT], 1);
            }
        }
    }
    __syncthreads();
    {
        int c = hall[t];
        goff[t] = c ? atomicAdd(&cursor[t], c) : 0;
        done[t] = 0;
    }

    for (int r = 0; r < RPB; ++r) {
        const long long rbase = bbase + (long long)r * ROUND;
        if (rbase >= cend) break;              // uniform across block
        h[t] = 0;
        __syncthreads();

        // Load round's edges into registers + round histogram.
        int4   dreg[EPT / 4];
        float4 vreg[EPT / 4];
        int    nval[EPT / 4];
        #pragma unroll
        for (int j = 0; j < EPT / 4; ++j) {
            long long e = rbase + ((long long)j * TPB + t) * 4;
            if (e + 4 <= cend) {
                dreg[j] = *reinterpret_cast<const int4*>(dst + e);
                vreg[j] = *reinterpret_cast<const float4*>(ea + e);
                nval[j] = 4;
            } else {
                int dd[4] = {0, 0, 0, 0};
                float vv[4] = {0.f, 0.f, 0.f, 0.f};
                int nv = 0;
                for (int q = 0; q < 4; ++q) {
                    long long ee = e + q;
                    if (ee < cend) { dd[q] = dst[ee]; vv[q] = ea[ee]; nv = q + 1; }
                }
                dreg[j] = make_int4(dd[0], dd[1], dd[2], dd[3]);
                vreg[j] = make_float4(vv[0], vv[1], vv[2], vv[3]);
                nval[j] = nv;
            }
            if (nval[j] > 0) atomicAdd(&h[dreg[j].x >> VSHIFT], 1);
            if (nval[j] > 1) atomicAdd(&h[dreg[j].y >> VSHIFT], 1);
            if (nval[j] > 2) atomicAdd(&h[dreg[j].z >> VSHIFT], 1);
            if (nval[j] > 3) atomicAdd(&h[dreg[j].w >> VSHIFT], 1);
        }
        __syncthreads();

        // Block-wide exclusive scan of h (NBMAX == TPB).
        {
            int v = h[t];
            int s = v;
            #pragma unroll
            for (int d_ = 1; d_ < 64; d_ <<= 1) {
                int u = __shfl_up(s, d_);
                if ((t & 63) >= d_) s += u;
            }
            if ((t & 63) == 63) wsum[t >> 6] = s;
            __syncthreads();
            int add = 0;
            #pragma unroll
            for (int w = 0; w < TPB / 64; ++w)
                if (w < (t >> 6)) add += wsum[w];
            int excl = s + add - v;
            pfx[t] = excl;
            pos[t] = excl;
            adj[t] = goff[t] + done[t] - excl;
            if (t == TPB - 1) round_total = excl + v;
        }
        __syncthreads();

        // Scatter pairs into bucket-sorted LDS staging.
        #pragma unroll
        for (int j = 0; j < EPT / 4; ++j) {
            int   dd[4] = {dreg[j].x, dreg[j].y, dreg[j].z, dreg[j].w};
            float vv[4] = {vreg[j].x, vreg[j].y, vreg[j].z, vreg[j].w};
            #pragma unroll
            for (int q = 0; q < 4; ++q) {
                if (q < nval[j]) {
                    int b = dd[q] >> VSHIFT;
                    int slot = atomicAdd(&pos[b], 1);
                    stage[slot] = pack_pair(dd[q], vv[q]);
                }
            }
        }
        __syncthreads();

        // Coalesced flush: consecutive slots -> consecutive global addresses.
        const int rt = round_total;
        for (int i = t; i < rt; i += TPB) {
            unsigned long long p = stage[i];
            int b = (int)((unsigned)(p & 0xffffffffull) >> VSHIFT);
            pairs[adj[b] + i] = p;
        }
        __syncthreads();
        done[t] += h[t];
    }
}

// One block per bucket: accumulate pairs into LDS, then add into cbar.
__global__ void accum_kernel(const unsigned long long* __restrict__ pairs,
                             const int* __restrict__ bases, int nb,
                             int chunk_count,
                             float* __restrict__ cbar, int n_vert) {
    __shared__ float acc[VBUCK];
    const int b = blockIdx.x;
    for (int t = threadIdx.x; t < VBUCK; t += blockDim.x) acc[t] = 0.f;
    __syncthreads();
    const int s = bases[b];
    const int e = (b + 1 < nb) ? bases[b + 1] : chunk_count;
    for (int i = s + threadIdx.x; i < e; i += blockDim.x) {
        unsigned long long p = pairs[i];
        int   dv = (int)(p & 0xffffffffull);
        float vv = __uint_as_float((unsigned)(p >> 32));
        atomicAdd(&acc[dv & (VBUCK - 1)], vv);
    }
    __syncthreads();
    const int vbase = b << VSHIFT;
    for (int t = threadIdx.x; t < VBUCK; t += blockDim.x) {
        int vi = vbase + t;
        if (vi < n_vert) cbar[vi] += acc[t];
    }
}

// Fallback: device-scope atomic scatter.
__global__ void scatter_add_dev_kernel(const int* __restrict__ dst,
                                       const float* __restrict__ ea,
                                       float* __restrict__ acc, int n_edges4) {
    int i = blockIdx.x * blockDim.x + threadIdx.x;
    const int stride = gridDim.x * blockDim.x;
    for (; i < n_edges4; i += stride) {
        int4   d = reinterpret_cast<const int4*>(dst)[i];
        float4 v = reinterpret_cast<const float4*>(ea)[i];
        atomicAdd(&acc[d.x], v.x);
        atomicAdd(&acc[d.y], v.y);
        atomicAdd(&acc[d.z], v.z);
        atomicAdd(&acc[d.w], v.w);
    }
}

// out rows: {A, b, x + w*(b - cbar)/A}; 4 vertices per thread, float4 I/O.
__global__ void update_kernel(const float* __restrict__ va,
                              const float* __restrict__ cbar,
                              const float* __restrict__ g,
                              float* __restrict__ out, int n) {
    int t = blockIdx.x * blockDim.x + threadIdx.x;
    const float w = g[0];
    int v0 = t * 4;
    if (v0 + 4 <= n) {
        float4 f0 = reinterpret_cast<const float4*>(va)[t * 3 + 0];
        float4 f1 = reinterpret_cast<const float4*>(va)[t * 3 + 1];
        float4 f2 = reinterpret_cast<const float4*>(va)[t * 3 + 2];
        float4 c  = reinterpret_cast<const float4*>(cbar)[t];
        // rows: (f0.x f0.y f0.z)(f0.w f1.x f1.y)(f1.z f1.w f2.x)(f2.y f2.z f2.w)
        float4 o0, o1, o2;
        o0.x = f0.x; o0.y = f0.y; o0.z = f0.z + w * (f0.y - c.x) / f0.x;
        o0.w = f0.w; o1.x = f1.x; o1.y = f1.y + w * (f1.x - c.y) / f0.w;
        o1.z = f1.z; o1.w = f1.w; o2.x = f2.x + w * (f1.w - c.z) / f1.z;
        o2.y = f2.y; o2.z = f2.z; o2.w = f2.w + w * (f2.z - c.w) / f2.y;
        reinterpret_cast<float4*>(out)[t * 3 + 0] = o0;
        reinterpret_cast<float4*>(out)[t * 3 + 1] = o1;
        reinterpret_cast<float4*>(out)[t * 3 + 2] = o2;
    } else {
        for (int i = v0; i < n; ++i) {
            float A = va[3 * i], b = va[3 * i + 1], x = va[3 * i + 2];
            out[3 * i]     = A;
            out[3 * i + 1] = b;
            out[3 * i + 2] = x + w * (b - cbar[i]) / A;
        }
    }
}

extern "C" void kernel_launch(void* const* d_in, const int* in_sizes, int n_in,
                              void* d_out, int out_size, void* d_ws, size_t ws_size,
                              hipStream_t stream) {
    const float* vertex_attr = (const float*)d_in[0];
    const int*   edgeij      = (const int*)d_in[1];   // row 0 = dst
    const float* edge_attr   = (const float*)d_in[2];
    const float* g           = (const float*)d_in[3];

    const int       n_vert = in_sizes[0] / 3;
    const long long n_edge = in_sizes[2];
    const int       nb     = (n_vert + VBUCK - 1) >> VSHIFT;

    // ws layout: [cbar][hist bases][cursors][pairs]
    size_t cbar_sz   = (size_t)n_vert * sizeof(float);
    size_t hist_off  = (cbar_sz + 255) & ~(size_t)255;
    size_t hist_sz   = (size_t)MAXCH * NBMAX * sizeof(int);
    size_t cur_off   = hist_off + hist_sz;
    size_t pairs_off = (cur_off + hist_sz + 255) & ~(size_t)255;

    float* cbar  = (float*)d_ws;
    int* hist    = (int*)((char*)d_ws + hist_off);
    int* cursor  = (int*)((char*)d_ws + cur_off);
    unsigned long long* pairs = (unsigned long long*)((char*)d_ws + pairs_off);

    long long cap = (ws_size > pairs_off) ? (long long)((ws_size - pairs_off) / 8) : 0;
    cap = (cap / PBLK) * PBLK;

    int nchunks = 0;
    long long chunk_edges = 0;
    if (cap >= PBLK && nb <= NBMAX) {
        nchunks = (int)((n_edge + cap - 1) / cap);
        if (nchunks <= MAXCH) {
            chunk_edges = (n_edge + nchunks - 1) / nchunks;
            chunk_edges = ((chunk_edges + PBLK - 1) / PBLK) * PBLK;
            if (chunk_edges > cap) chunk_edges = cap;
            nchunks = (int)((n_edge + chunk_edges - 1) / chunk_edges);
        } else {
            nchunks = 0;
        }
    }

    hipMemsetAsync(cbar, 0, cbar_sz, stream);

    if (nchunks == 0 || nchunks > MAXCH) {
        scatter_add_dev_kernel<<<4096, TPB, 0, stream>>>(edgeij, edge_attr, cbar,
                                                         (int)(n_edge / 4));
    } else {
        hipMemsetAsync(hist, 0, 2 * hist_sz, stream);
        int bpc = (int)(chunk_edges / HBLK);
        hist_kernel<<<nchunks * bpc, TPB, 0, stream>>>(edgeij, n_edge,
                                                       (int)chunk_edges, bpc, nb, hist);
        scan_kernel<<<1, 64, 0, stream>>>(hist, cursor, nchunks, nb);
        for (int c = 0; c < nchunks; ++c) {
            long long cstart = (long long)c * chunk_edges;
            long long cend   = cstart + chunk_edges;
            if (cend > n_edge) cend = n_edge;
            int pblocks = (int)((cend - cstart + PBLK - 1) / PBLK);
            partition_kernel<<<pblocks, TPB, 0, stream>>>(edgeij, edge_attr,
                                                          cstart, cend, nb,
                                                          cursor + c * NBMAX, pairs);
            accum_kernel<<<nb, 512, 0, stream>>>(pairs, hist + c * NBMAX, nb,
                                                 (int)(cend - cstart), cbar, n_vert);
        }
    }

    const int uthreads = (n_vert + 3) / 4;
    update_kernel<<<(uthreads + TPB - 1) / TPB, TPB, 0, stream>>>(
        vertex_attr, cbar, g, (float*)d_out, n_vert);
}

// Round 7
// 191.189 us; speedup vs baseline: 4.1254x; 1.4310x over previous
//
#include <hip/hip_runtime.h>

#define TPB    256
#define VSHIFT 12
#define VBUCK  (1 << VSHIFT)        // 4096 vertices per bucket
#define NBMAX  256                  // max buckets (1e6/4096 = 245); == TPB
#define EPT    16                   // edges/thread/round, partition
#define ROUND  (TPB * EPT)          // 4096 edges/round
#define RPB    4                    // rounds per block
#define PBLK   (ROUND * RPB)        // 16384 edges/block

__device__ __forceinline__ unsigned long long pack_pair(int d, float v) {
    return (unsigned long long)(unsigned)d |
           ((unsigned long long)__float_as_uint(v) << 32);
}

// Exclusive scan across TPB threads; also returns block total (uniform).
__device__ __forceinline__ int block_excl_scan(int v, int t, int* wsum, int* total) {
    int s = v;
    #pragma unroll
    for (int d = 1; d < 64; d <<= 1) {
        int u = __shfl_up(s, d);
        if ((t & 63) >= d) s += u;
    }
    if ((t & 63) == 63) wsum[t >> 6] = s;
    __syncthreads();
    int add = 0;
    #pragma unroll
    for (int w = 0; w < TPB / 64; ++w)
        if (w < (t >> 6)) add += wsum[w];
    int tot = wsum[0] + wsum[1] + wsum[2] + wsum[3];
    __syncthreads();                 // wsum safe for reuse
    *total = tot;
    return s + add - v;
}

// Per-partition-block bucket histogram, stored transposed: histp[b][blk].
__global__ void hist_blocks_kernel(const int* __restrict__ dst, long long n_edge,
                                   int nblk, int* __restrict__ histp) {
    __shared__ int h[NBMAX];
    const int t = threadIdx.x;
    h[t] = 0;
    __syncthreads();
    const long long bbase = (long long)blockIdx.x * PBLK;
    const long long bend0 = bbase + PBLK;
    const long long bend  = bend0 < n_edge ? bend0 : n_edge;
    #pragma unroll 4
    for (int j = 0; j < PBLK / TPB / 4; ++j) {
        long long e = bbase + ((long long)j * TPB + t) * 4;
        if (e + 4 <= bend) {
            int4 d = *reinterpret_cast<const int4*>(dst + e);
            atomicAdd(&h[d.x >> VSHIFT], 1);
            atomicAdd(&h[d.y >> VSHIFT], 1);
            atomicAdd(&h[d.z >> VSHIFT], 1);
            atomicAdd(&h[d.w >> VSHIFT], 1);
        } else {
            for (int q = 0; q < 4; ++q) {
                long long ee = e + q;
                if (ee < bend) atomicAdd(&h[dst[ee] >> VSHIFT], 1);
            }
        }
    }
    __syncthreads();
    histp[(size_t)t * nblk + blockIdx.x] = h[t];
}

// One block per bucket: exclusive-scan its row of per-block counts in place;
// write the bucket total.
__global__ void row_scan_kernel(int* __restrict__ histp, int nblk,
                                int* __restrict__ totals) {
    __shared__ int wsum[TPB / 64];
    const int t = threadIdx.x;
    int* row = histp + (size_t)blockIdx.x * nblk;
    int carry = 0;
    for (int base = 0; base < nblk; base += TPB) {
        int v = (base + t < nblk) ? row[base + t] : 0;
        int tot;
        int excl = block_excl_scan(v, t, wsum, &tot);
        if (base + t < nblk) row[base + t] = carry + excl;
        carry += tot;
        __syncthreads();
    }
    if (t == 0) totals[blockIdx.x] = carry;
}

// Exclusive scan of bucket totals -> bucket base offsets (base[NBMAX+1]).
__global__ void base_scan_kernel(const int* __restrict__ totals, int nb,
                                 int* __restrict__ base) {
    __shared__ int wsum[TPB / 64];
    const int t = threadIdx.x;
    int v = (t < nb) ? totals[t] : 0;
    int tot;
    int excl = block_excl_scan(v, t, wsum, &tot);
    base[t] = excl;
    if (t == TPB - 1) base[TPB] = excl + v;
}

// Partition edges into per-bucket pair regions. Offsets fully precomputed:
// no pass A, no global cursor atomics. LDS-staged bucket-sorted flush.
__global__ __launch_bounds__(TPB, 4)
void partition_kernel(const int* __restrict__ dst,
                      const float* __restrict__ ea,
                      long long n_edge, int nblk,
                      const int* __restrict__ histp,
                      const int* __restrict__ base,
                      unsigned long long* __restrict__ pairs) {
    __shared__ unsigned long long stage[ROUND];   // 32 KB, bucket-sorted pairs
    __shared__ int h[NBMAX];      // round histogram
    __shared__ int pos[NBMAX];    // round scatter cursors
    __shared__ int adj[NBMAX];    // goff+done-pfx per bucket
    __shared__ int goff[NBMAX];   // precomputed global base per bucket
    __shared__ int done[NBMAX];   // pairs already flushed per bucket
    __shared__ int wsum[TPB / 64];

    const int t   = threadIdx.x;
    const int blk = blockIdx.x;
    const long long bbase = (long long)blk * PBLK;
    const long long bend0 = bbase + PBLK;
    const long long bend  = bend0 < n_edge ? bend0 : n_edge;

    goff[t] = base[t] + histp[(size_t)t * nblk + blk];
    done[t] = 0;

    for (int r = 0; r < RPB; ++r) {
        const long long rbase = bbase + (long long)r * ROUND;
        if (rbase >= bend) break;              // uniform across block
        h[t] = 0;
        __syncthreads();

        // Load round's edges into registers + round histogram.
        int4   dreg[EPT / 4];
        float4 vreg[EPT / 4];
        int    nval[EPT / 4];
        #pragma unroll
        for (int j = 0; j < EPT / 4; ++j) {
            long long e = rbase + ((long long)j * TPB + t) * 4;
            if (e + 4 <= bend) {
                dreg[j] = *reinterpret_cast<const int4*>(dst + e);
                vreg[j] = *reinterpret_cast<const float4*>(ea + e);
                nval[j] = 4;
            } else {
                int dd[4] = {0, 0, 0, 0};
                float vv[4] = {0.f, 0.f, 0.f, 0.f};
                int nv = 0;
                for (int q = 0; q < 4; ++q) {
                    long long ee = e + q;
                    if (ee < bend) { dd[q] = dst[ee]; vv[q] = ea[ee]; nv = q + 1; }
                }
                dreg[j] = make_int4(dd[0], dd[1], dd[2], dd[3]);
                vreg[j] = make_float4(vv[0], vv[1], vv[2], vv[3]);
                nval[j] = nv;
            }
            if (nval[j] > 0) atomicAdd(&h[dreg[j].x >> VSHIFT], 1);
            if (nval[j] > 1) atomicAdd(&h[dreg[j].y >> VSHIFT], 1);
            if (nval[j] > 2) atomicAdd(&h[dreg[j].z >> VSHIFT], 1);
            if (nval[j] > 3) atomicAdd(&h[dreg[j].w >> VSHIFT], 1);
        }
        __syncthreads();

        int rt;
        int excl = block_excl_scan(h[t], t, wsum, &rt);
        pos[t] = excl;
        adj[t] = goff[t] + done[t] - excl;
        __syncthreads();

        // Scatter pairs into bucket-sorted LDS staging.
        #pragma unroll
        for (int j = 0; j < EPT / 4; ++j) {
            int   dd[4] = {dreg[j].x, dreg[j].y, dreg[j].z, dreg[j].w};
            float vv[4] = {vreg[j].x, vreg[j].y, vreg[j].z, vreg[j].w};
            #pragma unroll
            for (int q = 0; q < 4; ++q) {
                if (q < nval[j]) {
                    int b = dd[q] >> VSHIFT;
                    int slot = atomicAdd(&pos[b], 1);
                    stage[slot] = pack_pair(dd[q], vv[q]);
                }
            }
        }
        __syncthreads();

        // Coalesced flush: consecutive slots -> consecutive global addresses.
        for (int i = t; i < rt; i += TPB) {
            unsigned long long p = stage[i];
            int b = (int)((unsigned)(p & 0xffffffffull) >> VSHIFT);
            pairs[(size_t)(adj[b] + i)] = p;
        }
        __syncthreads();
        done[t] += h[t];
    }
}

// One block per bucket: accumulate pairs into LDS, then fused vertex update.
__global__ void accum_update_kernel(const unsigned long long* __restrict__ pairs,
                                    const int* __restrict__ base,
                                    const float* __restrict__ va,
                                    const float* __restrict__ g,
                                    float* __restrict__ out, int n_vert) {
    __shared__ __align__(16) float acc[VBUCK];
    const int b = blockIdx.x;
    const int T = blockDim.x;                  // 1024
    for (int t = threadIdx.x; t < VBUCK; t += T) acc[t] = 0.f;
    __syncthreads();
    const int s = base[b];
    const int e = base[b + 1];
    for (int i = s + threadIdx.x; i < e; i += T) {
        unsigned long long p = pairs[i];
        atomicAdd(&acc[(int)(p & (VBUCK - 1))],
                  __uint_as_float((unsigned)(p >> 32)));
    }
    __syncthreads();

    const float w = g[0];
    const int vbase = b << VSHIFT;
    const int t = threadIdx.x;
    const int v0 = vbase + t * 4;
    if (v0 + 4 <= n_vert) {
        const int gt = v0 >> 2;
        float4 f0 = reinterpret_cast<const float4*>(va)[gt * 3 + 0];
        float4 f1 = reinterpret_cast<const float4*>(va)[gt * 3 + 1];
        float4 f2 = reinterpret_cast<const float4*>(va)[gt * 3 + 2];
        float4 c  = reinterpret_cast<const float4*>(acc)[t];
        float4 o0, o1, o2;
        o0.x = f0.x; o0.y = f0.y; o0.z = f0.z + w * (f0.y - c.x) / f0.x;
        o0.w = f0.w; o1.x = f1.x; o1.y = f1.y + w * (f1.x - c.y) / f0.w;
        o1.z = f1.z; o1.w = f1.w; o2.x = f2.x + w * (f1.w - c.z) / f1.z;
        o2.y = f2.y; o2.z = f2.z; o2.w = f2.w + w * (f2.z - c.w) / f2.y;
        reinterpret_cast<float4*>(out)[gt * 3 + 0] = o0;
        reinterpret_cast<float4*>(out)[gt * 3 + 1] = o1;
        reinterpret_cast<float4*>(out)[gt * 3 + 2] = o2;
    } else {
        for (int i = v0; i < n_vert && i < v0 + 4; ++i) {
            float A = va[3 * i], bb = va[3 * i + 1], x = va[3 * i + 2];
            out[3 * i]     = A;
            out[3 * i + 1] = bb;
            out[3 * i + 2] = x + w * (bb - acc[i - vbase]) / A;
        }
    }
}

// ---- fallback path (insufficient scratch): device-scope atomics ----
__global__ void scatter_add_dev_kernel(const int* __restrict__ dst,
                                       const float* __restrict__ ea,
                                       float* __restrict__ acc, int n_edges4) {
    int i = blockIdx.x * blockDim.x + threadIdx.x;
    const int stride = gridDim.x * blockDim.x;
    for (; i < n_edges4; i += stride) {
        int4   d = reinterpret_cast<const int4*>(dst)[i];
        float4 v = reinterpret_cast<const float4*>(ea)[i];
        atomicAdd(&acc[d.x], v.x);
        atomicAdd(&acc[d.y], v.y);
        atomicAdd(&acc[d.z], v.z);
        atomicAdd(&acc[d.w], v.w);
    }
}

__global__ void update_kernel(const float* __restrict__ va,
                              const float* __restrict__ cbar,
                              const float* __restrict__ g,
                              float* __restrict__ out, int n) {
    int i = blockIdx.x * blockDim.x + threadIdx.x;
    if (i >= n) return;
    float A = va[3 * i], b = va[3 * i + 1], x = va[3 * i + 2];
    out[3 * i]     = A;
    out[3 * i + 1] = b;
    out[3 * i + 2] = x + g[0] * (b - cbar[i]) / A;
}

extern "C" void kernel_launch(void* const* d_in, const int* in_sizes, int n_in,
                              void* d_out, int out_size, void* d_ws, size_t ws_size,
                              hipStream_t stream) {
    const float* vertex_attr = (const float*)d_in[0];
    const int*   edgeij      = (const int*)d_in[1];   // row 0 = dst
    const float* edge_attr   = (const float*)d_in[2];
    const float* g           = (const float*)d_in[3];

    const int       n_vert = in_sizes[0] / 3;
    const long long n_edge = in_sizes[2];
    const int       nb     = (n_vert + VBUCK - 1) >> VSHIFT;
    const int       nblk   = (int)((n_edge + PBLK - 1) / PBLK);

    // ws layout: [histp: NBMAX*nblk][totals: NBMAX][base: TPB+1][pairs: n_edge]
    size_t histp_sz   = (size_t)NBMAX * nblk * sizeof(int);
    size_t totals_off = (histp_sz + 255) & ~(size_t)255;
    size_t base_off   = totals_off + NBMAX * sizeof(int);
    size_t pairs_off  = (base_off + (TPB + 1) * sizeof(int) + 255) & ~(size_t)255;
    size_t need       = pairs_off + (size_t)n_edge * sizeof(unsigned long long);

    if (ws_size >= need && nb <= NBMAX) {
        int* histp  = (int*)d_ws;
        int* totals = (int*)((char*)d_ws + totals_off);
        int* basep  = (int*)((char*)d_ws + base_off);
        unsigned long long* pairs =
            (unsigned long long*)((char*)d_ws + pairs_off);

        hist_blocks_kernel<<<nblk, TPB, 0, stream>>>(edgeij, n_edge, nblk, histp);
        row_scan_kernel<<<nb, TPB, 0, stream>>>(histp, nblk, totals);
        base_scan_kernel<<<1, TPB, 0, stream>>>(totals, nb, basep);
        partition_kernel<<<nblk, TPB, 0, stream>>>(edgeij, edge_attr, n_edge,
                                                   nblk, histp, basep, pairs);
        accum_update_kernel<<<nb, 1024, 0, stream>>>(pairs, basep, vertex_attr,
                                                     g, (float*)d_out, n_vert);
    } else {
        float* cbar = (float*)d_ws;
        hipMemsetAsync(cbar, 0, (size_t)n_vert * sizeof(float), stream);
        scatter_add_dev_kernel<<<4096, TPB, 0, stream>>>(edgeij, edge_attr, cbar,
                                                         (int)(n_edge / 4));
        update_kernel<<<(n_vert + TPB - 1) / TPB, TPB, 0, stream>>>(
            vertex_attr, cbar, g, (float*)d_out, n_vert);
    }
}